// Round 4
// baseline (240.494 us; speedup 1.0000x reference)
//
#include <hip/hip_runtime.h>
#include <hip/hip_bf16.h>
#include <cstdint>

constexpr int Bc = 2, Sc = 2048, Dc = 1024, Hc = 16;
constexpr int Mtok = Bc * Sc;  // 4096 token rows

typedef __bf16 bf16;
typedef __bf16 bf16x4 __attribute__((ext_vector_type(4)));
typedef __bf16 bf16x8 __attribute__((ext_vector_type(8)));
typedef float  f32x4  __attribute__((ext_vector_type(4)));

// async global->LDS, 16B per lane; LDS dest = wave-uniform base + lane*16
__device__ __forceinline__ void gld_lds16(const bf16* g, bf16* l) {
  __builtin_amdgcn_global_load_lds(
      (__attribute__((address_space(1))) void*)(void*)g,
      (__attribute__((address_space(3))) void*)l, 16, 0, 0);
}

// ---------------------------------------------------------------------------
// One-time fp32 -> bf16 conversion of q,k,v and the 4 weight matrices.
// ---------------------------------------------------------------------------
__global__ __launch_bounds__(256) void convert_all(
    const float* __restrict__ q, const float* __restrict__ k,
    const float* __restrict__ v, const float* __restrict__ wq,
    const float* __restrict__ wk, const float* __restrict__ wv,
    const float* __restrict__ wo, bf16* __restrict__ ws)
{
  constexpr size_t NQ = (size_t)Mtok * Dc;
  constexpr size_t NW = (size_t)Dc * Dc;
  const size_t e = ((size_t)blockIdx.x * 256 + threadIdx.x) * 8;
  const float* src; bf16* dst;
  if (e < 3 * NQ) {
    src = (e < NQ) ? q + e : (e < 2 * NQ) ? k + (e - NQ) : v + (e - 2 * NQ);
    dst = ws + e;
  } else {
    const size_t w = e - 3 * NQ;
    const float* wsrc = (w < NW) ? wq : (w < 2 * NW) ? wk : (w < 3 * NW) ? wv : wo;
    src = wsrc + (w & (NW - 1));
    dst = ws + 5 * NQ + w;
  }
  f32x4 a = ((const f32x4*)src)[0];
  f32x4 b = ((const f32x4*)src)[1];
  bf16x8 t;
  t[0]=(bf16)a[0]; t[1]=(bf16)a[1]; t[2]=(bf16)a[2]; t[3]=(bf16)a[3];
  t[4]=(bf16)b[0]; t[5]=(bf16)b[1]; t[6]=(bf16)b[2]; t[7]=(bf16)b[3];
  *(bf16x8*)dst = t;
}

// ---------------------------------------------------------------------------
// Fused Q/K/V projection GEMM: 128x128 tile, BK=64 (halved barrier count),
// global_load_lds width=16, unpadded LDS. grid (32,8,3).
// z==2 (V) writes its output TRANSPOSED to Vt (B, D, S) with packed 8B stores
// (rows are contiguous in the accumulator's i index) — kills transpose_v.
// ---------------------------------------------------------------------------
__global__ __launch_bounds__(256) void gemm_qkv(
    const bf16* __restrict__ Aq, const bf16* __restrict__ Ak,
    const bf16* __restrict__ Av, const bf16* __restrict__ Wb,
    const float* __restrict__ bq, const float* __restrict__ bk,
    const float* __restrict__ bv,
    bf16* __restrict__ Yq, bf16* __restrict__ Yk, bf16* __restrict__ Vt)
{
  __shared__ __attribute__((aligned(16))) bf16 As[128 * 64];
  __shared__ __attribute__((aligned(16))) bf16 Bs[128 * 64];

  const int z = blockIdx.z;
  const bf16*  A    = (z == 0) ? Aq : (z == 1) ? Ak : Av;
  const bf16*  Wz   = Wb + (size_t)z * Dc * Dc;
  const float* bias = (z == 0) ? bq : (z == 1) ? bk : bv;

  const int m0 = blockIdx.x * 128, n0 = blockIdx.y * 128;
  const int tid = threadIdx.x, wave = tid >> 6, lane = tid & 63;
  const int quad = lane >> 4, l16 = lane & 15;
  const int rw = wave >> 1, cw = wave & 1;
  // staging: pass s covers rows s*32 + wave*8 + (lane>>3), col (lane&7)*8
  const int srow = wave * 8 + (lane >> 3);
  const int scol = (lane & 7) * 8;

  f32x4 acc[4][4] = {};

  for (int k0 = 0; k0 < Dc; k0 += 64) {
#pragma unroll
    for (int s = 0; s < 4; ++s) {
      const int row = s * 32 + srow;
      bf16* base = &As[s * 2048 + wave * 512];
      gld_lds16(A  + (size_t)(m0 + row) * Dc + k0 + scol, base);
      bf16* baseB = &Bs[s * 2048 + wave * 512];
      gld_lds16(Wz + (size_t)(n0 + row) * Dc + k0 + scol, baseB);
    }
    __syncthreads();
#pragma unroll
    for (int ks = 0; ks < 2; ++ks) {
      bf16x8 af[4];
#pragma unroll
      for (int rt = 0; rt < 4; ++rt)
        af[rt] = *(const bf16x8*)&As[(rw * 64 + rt * 16 + l16) * 64 + ks * 32 + quad * 8];
#pragma unroll
      for (int ct = 0; ct < 4; ++ct) {
        bf16x8 bfr = *(const bf16x8*)&Bs[(cw * 64 + ct * 16 + l16) * 64 + ks * 32 + quad * 8];
#pragma unroll
        for (int rt = 0; rt < 4; ++rt)
          acc[rt][ct] = __builtin_amdgcn_mfma_f32_16x16x32_bf16(af[rt], bfr, acc[rt][ct], 0, 0, 0);
      }
    }
    __syncthreads();
  }

  if (z < 2) {
    bf16* Y = (z == 0) ? Yq : Yk;
#pragma unroll
    for (int ct = 0; ct < 4; ++ct) {
      const int col = n0 + cw * 64 + ct * 16 + l16;
      const float bvv = bias[col];
#pragma unroll
      for (int rt = 0; rt < 4; ++rt)
#pragma unroll
        for (int i = 0; i < 4; ++i) {
          const int row = m0 + rw * 64 + rt * 16 + quad * 4 + i;
          Y[(size_t)row * Dc + col] = (bf16)(acc[rt][ct][i] + bvv);
        }
    }
  } else {
    // V: write transposed -> Vt[(b*Dc + col)*Sc + s], i-axis contiguous
#pragma unroll
    for (int ct = 0; ct < 4; ++ct) {
      const int col = n0 + cw * 64 + ct * 16 + l16;
      const float bvv = bias[col];
#pragma unroll
      for (int rt = 0; rt < 4; ++rt) {
        const int row0 = m0 + rw * 64 + rt * 16 + quad * 4;  // multiple of 4
        const int bb = row0 >> 11, s0 = row0 & 2047;
        bf16x4 pk;
#pragma unroll
        for (int i = 0; i < 4; ++i) pk[i] = (bf16)(acc[rt][ct][i] + bvv);
        *(bf16x4*)&Vt[((size_t)bb * Dc + col) * Sc + s0] = pk;
      }
    }
  }
}

// ---------------------------------------------------------------------------
// O-projection GEMM: 64x128 tile, BK=64, m97 staging, fp32 out. 512 blocks.
// ---------------------------------------------------------------------------
__global__ __launch_bounds__(256) void gemm_o(
    const bf16* __restrict__ A, const bf16* __restrict__ Wz,
    const float* __restrict__ bias, float* __restrict__ Y)
{
  __shared__ __attribute__((aligned(16))) bf16 As[64 * 64];
  __shared__ __attribute__((aligned(16))) bf16 Bs[128 * 64];

  const int m0 = blockIdx.x * 64, n0 = blockIdx.y * 128;
  const int tid = threadIdx.x, wave = tid >> 6, lane = tid & 63;
  const int quad = lane >> 4, l16 = lane & 15;
  const int srow = wave * 8 + (lane >> 3);
  const int scol = (lane & 7) * 8;

  f32x4 acc[4][2] = {};

  for (int k0 = 0; k0 < Dc; k0 += 64) {
#pragma unroll
    for (int s = 0; s < 2; ++s)
      gld_lds16(A + (size_t)(m0 + s * 32 + srow) * Dc + k0 + scol,
                &As[s * 2048 + wave * 512]);
#pragma unroll
    for (int s = 0; s < 4; ++s)
      gld_lds16(Wz + (size_t)(n0 + s * 32 + srow) * Dc + k0 + scol,
                &Bs[s * 2048 + wave * 512]);
    __syncthreads();
#pragma unroll
    for (int ks = 0; ks < 2; ++ks) {
      bf16x8 af[4];
#pragma unroll
      for (int rt = 0; rt < 4; ++rt)
        af[rt] = *(const bf16x8*)&As[(rt * 16 + l16) * 64 + ks * 32 + quad * 8];
#pragma unroll
      for (int ct = 0; ct < 2; ++ct) {
        bf16x8 bfr = *(const bf16x8*)&Bs[(wave * 32 + ct * 16 + l16) * 64 + ks * 32 + quad * 8];
#pragma unroll
        for (int rt = 0; rt < 4; ++rt)
          acc[rt][ct] = __builtin_amdgcn_mfma_f32_16x16x32_bf16(af[rt], bfr, acc[rt][ct], 0, 0, 0);
      }
    }
    __syncthreads();
  }

#pragma unroll
  for (int ct = 0; ct < 2; ++ct) {
    const int col = n0 + wave * 32 + ct * 16 + l16;
    const float bvv = bias[col];
#pragma unroll
    for (int rt = 0; rt < 4; ++rt)
#pragma unroll
      for (int i = 0; i < 4; ++i) {
        const int row = m0 + rt * 16 + quad * 4 + i;
        Y[(size_t)row * Dc + col] = acc[rt][ct][i] + bvv;
      }
  }
}

// ---------------------------------------------------------------------------
// Fallback GEMM (fp32-staging 128x128, reg prefetch) for small workspaces.
// ---------------------------------------------------------------------------
template <bool AF32, bool BF32, bool OUTF32>
__global__ __launch_bounds__(256) void gemm128(
    const void* __restrict__ Av, const void* __restrict__ Bv,
    const float* __restrict__ bias, void* __restrict__ Yv,
    int M, int N, int K)
{
  __shared__ __attribute__((aligned(16))) bf16 As[2][128][40];
  __shared__ __attribute__((aligned(16))) bf16 Bs[2][128][40];

  const int m0 = blockIdx.x * 128, n0 = blockIdx.y * 128;
  const int tid = threadIdx.x, wave = tid >> 6, lane = tid & 63;
  const int quad = lane >> 4, l16 = lane & 15;
  const int rw = wave >> 1, cw = wave & 1;
  const int srow = tid >> 1, sc = (tid & 1) * 16;

  f32x4 acc[4][4] = {};

  auto load = [&](const void* P, bool f32, int r0, int k0, bf16x8& lo, bf16x8& hi) {
    if (f32) {
      const float* s = (const float*)P + (size_t)(r0 + srow) * K + k0 + sc;
      f32x4 a0 = ((const f32x4*)s)[0], a1 = ((const f32x4*)s)[1];
      f32x4 a2 = ((const f32x4*)s)[2], a3 = ((const f32x4*)s)[3];
      lo[0]=(bf16)a0[0]; lo[1]=(bf16)a0[1]; lo[2]=(bf16)a0[2]; lo[3]=(bf16)a0[3];
      lo[4]=(bf16)a1[0]; lo[5]=(bf16)a1[1]; lo[6]=(bf16)a1[2]; lo[7]=(bf16)a1[3];
      hi[0]=(bf16)a2[0]; hi[1]=(bf16)a2[1]; hi[2]=(bf16)a2[2]; hi[3]=(bf16)a2[3];
      hi[4]=(bf16)a3[0]; hi[5]=(bf16)a3[1]; hi[6]=(bf16)a3[2]; hi[7]=(bf16)a3[3];
    } else {
      const bf16* s = (const bf16*)P + (size_t)(r0 + srow) * K + k0 + sc;
      lo = ((const bf16x8*)s)[0]; hi = ((const bf16x8*)s)[1];
    }
  };

  bf16x8 alo, ahi, blo, bhi;
  load(Av, AF32, m0, 0, alo, ahi); load(Bv, BF32, n0, 0, blo, bhi);
  *(bf16x8*)&As[0][srow][sc] = alo; *(bf16x8*)&As[0][srow][sc + 8] = ahi;
  *(bf16x8*)&Bs[0][srow][sc] = blo; *(bf16x8*)&Bs[0][srow][sc + 8] = bhi;

  const int NIT = K >> 5;
  for (int it = 0; it < NIT; ++it) {
    __syncthreads();
    const int cur = it & 1;
    const bool pf = (it + 1) < NIT;
    if (pf) { load(Av, AF32, m0, (it+1)*32, alo, ahi); load(Bv, BF32, n0, (it+1)*32, blo, bhi); }

    bf16x8 af[4];
#pragma unroll
    for (int rt = 0; rt < 4; ++rt)
      af[rt] = *(const bf16x8*)&As[cur][rw * 64 + rt * 16 + l16][quad * 8];
#pragma unroll
    for (int ct = 0; ct < 4; ++ct) {
      bf16x8 bfr = *(const bf16x8*)&Bs[cur][cw * 64 + ct * 16 + l16][quad * 8];
#pragma unroll
      for (int rt = 0; rt < 4; ++rt)
        acc[rt][ct] = __builtin_amdgcn_mfma_f32_16x16x32_bf16(af[rt], bfr, acc[rt][ct], 0, 0, 0);
    }
    if (pf) {
      const int nxt = cur ^ 1;
      *(bf16x8*)&As[nxt][srow][sc] = alo; *(bf16x8*)&As[nxt][srow][sc + 8] = ahi;
      *(bf16x8*)&Bs[nxt][srow][sc] = blo; *(bf16x8*)&Bs[nxt][srow][sc + 8] = bhi;
    }
  }

#pragma unroll
  for (int ct = 0; ct < 4; ++ct) {
    const int col = n0 + cw * 64 + ct * 16 + l16;
    const float bvv = bias[col];
#pragma unroll
    for (int rt = 0; rt < 4; ++rt)
#pragma unroll
      for (int i = 0; i < 4; ++i) {
        const int row = m0 + rw * 64 + rt * 16 + quad * 4 + i;
        const float vv = acc[rt][ct][i] + bvv;
        if constexpr (OUTF32) ((float*)Yv)[(size_t)row * N + col] = vv;
        else                  ((bf16*)Yv)[(size_t)row * N + col] = (bf16)vv;
      }
  }
}

// ---------------------------------------------------------------------------
// Transpose V (fallback path only): (B*S, D) -> (B, D, S).
// ---------------------------------------------------------------------------
__global__ __launch_bounds__(256) void transpose_v(
    const bf16* __restrict__ in, bf16* __restrict__ out)
{
  __shared__ __attribute__((aligned(16))) bf16 tile[64][72];
  const int s0 = blockIdx.x * 64, d0 = blockIdx.y * 64, b = blockIdx.z;
  const int t = threadIdx.x, r = t >> 2, c = (t & 3) * 16;

  const bf16* src = in + (size_t)(b * Sc + s0 + r) * Dc + d0 + c;
  *(bf16x8*)&tile[r][c]     = ((const bf16x8*)src)[0];
  *(bf16x8*)&tile[r][c + 8] = ((const bf16x8*)src)[1];
  __syncthreads();

  bf16x8 t0, t1;
#pragma unroll
  for (int j = 0; j < 8; ++j) t0[j] = tile[c + j][r];
#pragma unroll
  for (int j = 0; j < 8; ++j) t1[j] = tile[c + 8 + j][r];
  bf16* dst = out + (size_t)(b * Dc + d0 + r) * Sc + s0 + c;
  ((bf16x8*)dst)[0] = t0;
  ((bf16x8*)dst)[1] = t1;
}

// ---------------------------------------------------------------------------
// Causal flash attention v4.
//  - 64 q-rows/block, 256 thr = 4 waves; 1024 blocks, LDS 43.5 KB -> 3 blk/CU
//    (12 waves/CU): decorrelated blocks fill each other's MFMA/VALU bubbles.
//  - round-balanced qt permutation: each CU slot sums to ~66 iterations.
//  - S^T = K*Q^T (swapped MFMA operands, same LDS reads): C-layout reg axis =
//    consecutive KEYS -> Ps written as packed bf16x4 (4x ds_write_b64).
//  - no running max; rowsums via MFMA(ones); K/V dbuf + reg prefetch.
//  - XCD clustering: blockIdx.x = bh -> (b,h) pinned to one XCD's L2.
// ---------------------------------------------------------------------------
__global__ __launch_bounds__(256) void attn4(
    const bf16* __restrict__ Q, const bf16* __restrict__ K,
    const bf16* __restrict__ Vt, bf16* __restrict__ O)
{
  __shared__ __attribute__((aligned(16))) bf16 Ks[2][64][68];
  __shared__ __attribute__((aligned(16))) bf16 Vs[2][64][68];   // [d][key]
  __shared__ __attribute__((aligned(16))) bf16 Ps[4][16][68];   // per-wave

  const int bh = blockIdx.x, b = bh >> 4, h = bh & 15;
  const int qy = blockIdx.y;
  // balance rounds: qt in {t, 15-t, 16+t, 31-t} across dispatch rounds
  const int qt = (qy & 8) ? ((qy & 24) | (7 - (qy & 7))) : qy;
  const int q0 = qt * 64;
  const int nkb = qt + 1;

  const int tid = threadIdx.x, wave = tid >> 6, lane = tid & 63;
  const int quad = lane >> 4, l16 = lane & 15;
  const int sr = tid >> 2, sc4 = (tid & 3) * 16;   // staging 64 x 64

  const bf16 onec = (bf16)1.0f;
  const bf16x8 ones = {onec, onec, onec, onec, onec, onec, onec, onec};

  // Q fragment in registers (B-operand of S^T): rows wave*16+l16
  const bf16* qrow = Q + (size_t)(b * Sc + q0 + wave * 16 + l16) * Dc + h * 64 + quad * 8;
  const bf16x8 aq0 = *(const bf16x8*)qrow;
  const bf16x8 aq1 = *(const bf16x8*)(qrow + 32);

  f32x4 oacc[4] = {{0,0,0,0},{0,0,0,0},{0,0,0,0},{0,0,0,0}};
  f32x4 lacc = {0, 0, 0, 0};

  {
    const bf16* ksrc = K + (size_t)(b * Sc + sr) * Dc + h * 64 + sc4;
    ((bf16x8*)&Ks[0][sr][sc4])[0] = ((const bf16x8*)ksrc)[0];
    ((bf16x8*)&Ks[0][sr][sc4])[1] = ((const bf16x8*)ksrc)[1];
    const bf16* vsrc = Vt + (size_t)(b * Dc + h * 64 + sr) * Sc + sc4;
    ((bf16x8*)&Vs[0][sr][sc4])[0] = ((const bf16x8*)vsrc)[0];
    ((bf16x8*)&Vs[0][sr][sc4])[1] = ((const bf16x8*)vsrc)[1];
  }

  for (int kb = 0; kb < nkb; ++kb) {
    __syncthreads();
    const int cur = kb & 1;
    const bool pf = (kb + 1) < nkb;
    bf16x8 kp0, kp1, vp0, vp1;
    if (pf) {
      const bf16* ksrc = K + (size_t)(b * Sc + (kb + 1) * 64 + sr) * Dc + h * 64 + sc4;
      kp0 = ((const bf16x8*)ksrc)[0]; kp1 = ((const bf16x8*)ksrc)[1];
      const bf16* vsrc = Vt + (size_t)(b * Dc + h * 64 + sr) * Sc + (kb + 1) * 64 + sc4;
      vp0 = ((const bf16x8*)vsrc)[0]; vp1 = ((const bf16x8*)vsrc)[1];
    }

    // S^T = K * Q^T : A = K-frag (m=key), B = Q-frag (n=q). Same LDS reads.
    f32x4 s[4] = {{0,0,0,0},{0,0,0,0},{0,0,0,0},{0,0,0,0}};
#pragma unroll
    for (int d2 = 0; d2 < 2; ++d2) {
      const bf16x8 bq = d2 ? aq1 : aq0;
#pragma unroll
      for (int ct = 0; ct < 4; ++ct) {
        bf16x8 ak = *(const bf16x8*)&Ks[cur][ct * 16 + l16][d2 * 32 + quad * 8];
        s[ct] = __builtin_amdgcn_mfma_f32_16x16x32_bf16(ak, bq, s[ct], 0, 0, 0);
      }
    }

    // exp + (diagonal-only) causal mask; reg axis i = consecutive keys ->
    // packed A-layout write: Ps[q=l16][key = ct*16+quad*4+i]
    if (kb == nkb - 1) {
      const int qcol = wave * 16 + l16;
#pragma unroll
      for (int ct = 0; ct < 4; ++ct) {
        const int key0 = ct * 16 + quad * 4;
        bf16x4 pk;
#pragma unroll
        for (int i = 0; i < 4; ++i)
          pk[i] = (bf16)((key0 + i > qcol) ? 0.f : __expf(s[ct][i] * 0.125f));
        *(bf16x4*)&Ps[wave][l16][key0] = pk;
      }
    } else {
#pragma unroll
      for (int ct = 0; ct < 4; ++ct) {
        bf16x4 pk;
#pragma unroll
        for (int i = 0; i < 4; ++i) pk[i] = (bf16)__expf(s[ct][i] * 0.125f);
        *(bf16x4*)&Ps[wave][l16][ct * 16 + quad * 4] = pk;
      }
    }

    const bf16x8 ap0 = *(const bf16x8*)&Ps[wave][l16][quad * 8];
    const bf16x8 ap1 = *(const bf16x8*)&Ps[wave][l16][32 + quad * 8];

    lacc = __builtin_amdgcn_mfma_f32_16x16x32_bf16(ap0, ones, lacc, 0, 0, 0);
    lacc = __builtin_amdgcn_mfma_f32_16x16x32_bf16(ap1, ones, lacc, 0, 0, 0);

#pragma unroll
    for (int d2 = 0; d2 < 2; ++d2) {
      const bf16x8 ap = d2 ? ap1 : ap0;
#pragma unroll
      for (int ct = 0; ct < 4; ++ct) {
        bf16x8 bv = *(const bf16x8*)&Vs[cur][ct * 16 + l16][d2 * 32 + quad * 8];
        oacc[ct] = __builtin_amdgcn_mfma_f32_16x16x32_bf16(ap, bv, oacc[ct], 0, 0, 0);
      }
    }

    if (pf) {
      const int nxt = cur ^ 1;
      ((bf16x8*)&Ks[nxt][sr][sc4])[0] = kp0; ((bf16x8*)&Ks[nxt][sr][sc4])[1] = kp1;
      ((bf16x8*)&Vs[nxt][sr][sc4])[0] = vp0; ((bf16x8*)&Vs[nxt][sr][sc4])[1] = vp1;
    }
  }

  f32x4 rl;
#pragma unroll
  for (int i = 0; i < 4; ++i) rl[i] = 1.0f / lacc[i];
#pragma unroll
  for (int ct = 0; ct < 4; ++ct)
#pragma unroll
    for (int i = 0; i < 4; ++i)
      O[(size_t)(b * Sc + q0 + wave * 16 + quad * 4 + i) * Dc + h * 64 + ct * 16 + l16] =
          (bf16)(oacc[ct][i] * rl[i]);
}

// ---------------------------------------------------------------------------
extern "C" void kernel_launch(void* const* d_in, const int* in_sizes, int n_in,
                              void* d_out, int out_size, void* d_ws, size_t ws_size,
                              hipStream_t stream)
{
  const float* q  = (const float*)d_in[0];
  const float* k  = (const float*)d_in[1];
  const float* v  = (const float*)d_in[2];
  // d_in[3] = causal tril mask — deterministic, applied analytically
  const float* wq = (const float*)d_in[4];
  const float* bq = (const float*)d_in[5];
  const float* wk = (const float*)d_in[6];
  const float* bk = (const float*)d_in[7];
  const float* wv = (const float*)d_in[8];
  const float* bv = (const float*)d_in[9];
  const float* wo = (const float*)d_in[10];
  const float* bo = (const float*)d_in[11];
  float* out = (float*)d_out;

  constexpr size_t NQ = (size_t)Mtok * Dc;
  constexpr size_t NW = (size_t)Dc * Dc;
  bf16* W = (bf16*)d_ws;
  const dim3 ga(Hc * Bc, 32);                // 1024 attn blocks
  const dim3 gt(Sc / 64, Dc / 64, Bc);

  const bool fancy = ws_size >= (size_t)(6 * NQ + 4 * NW) * 2;  // 58.7 MB
  if (fancy) {
    bf16* xq = W;             // dead after gemm_qkv -> reused as AO
    bf16* xk = W + NQ;
    bf16* xv = W + 2 * NQ;
    bf16* Qp = W + 3 * NQ;
    bf16* Kp = W + 4 * NQ;
    bf16* wb = W + 5 * NQ;    // wq,wk,wv,wo bf16 (4*NW)
    bf16* Vt = W + 5 * NQ + 4 * NW;  // fresh region (no aliasing with xv!)
    bf16* AO = W;             // reuse xq

    convert_all<<<8192, 256, 0, stream>>>(q, k, v, wq, wk, wv, wo, W);
    gemm_qkv<<<dim3(Mtok / 128, Dc / 128, 3), 256, 0, stream>>>(
        xq, xk, xv, wb, bq, bk, bv, Qp, Kp, Vt);
    attn4<<<ga, 256, 0, stream>>>(Qp, Kp, Vt, AO);
    gemm_o<<<dim3(Mtok / 64, Dc / 128), 256, 0, stream>>>(AO, wb + 3 * NW, bo, out);
  } else {
    // fallback: fp32 staging conversion inside the GEMMs, separate transpose
    bf16* Qp = W;
    bf16* Kp = W + NQ;
    bf16* Vp = W + 2 * NQ;
    bf16* Vt = W + 3 * NQ;
    bf16* AO = W + 4 * NQ;
    const dim3 gg(Mtok / 128, Dc / 128);
    gemm128<true, true, false><<<gg, 256, 0, stream>>>(q, wq, bq, Qp, Mtok, Dc, Dc);
    gemm128<true, true, false><<<gg, 256, 0, stream>>>(k, wk, bk, Kp, Mtok, Dc, Dc);
    gemm128<true, true, false><<<gg, 256, 0, stream>>>(v, wv, bv, Vp, Mtok, Dc, Dc);
    transpose_v<<<gt, 256, 0, stream>>>(Vp, Vt);
    attn4<<<ga, 256, 0, stream>>>(Qp, Kp, Vt, AO);
    gemm128<false, true, true><<<gg, 256, 0, stream>>>(AO, wo, bo, out, Mtok, Dc, Dc);
  }
}

// Round 5
// 235.095 us; speedup vs baseline: 1.0230x; 1.0230x over previous
//
#include <hip/hip_runtime.h>
#include <hip/hip_bf16.h>
#include <cstdint>

constexpr int Bc = 2, Sc = 2048, Dc = 1024, Hc = 16;
constexpr int Mtok = Bc * Sc;  // 4096 token rows

typedef __bf16 bf16;
typedef __bf16 bf16x4 __attribute__((ext_vector_type(4)));
typedef __bf16 bf16x8 __attribute__((ext_vector_type(8)));
typedef float  f32x4  __attribute__((ext_vector_type(4)));

// async global->LDS, 16B per lane; LDS dest = wave-uniform base + lane*16
__device__ __forceinline__ void gld_lds16(const bf16* g, bf16* l) {
  __builtin_amdgcn_global_load_lds(
      (__attribute__((address_space(1))) void*)(void*)g,
      (__attribute__((address_space(3))) void*)l, 16, 0, 0);
}

// ---------------------------------------------------------------------------
// One-time fp32 -> bf16 conversion of q,k,v and the 4 weight matrices.
// ---------------------------------------------------------------------------
__global__ __launch_bounds__(256) void convert_all(
    const float* __restrict__ q, const float* __restrict__ k,
    const float* __restrict__ v, const float* __restrict__ wq,
    const float* __restrict__ wk, const float* __restrict__ wv,
    const float* __restrict__ wo, bf16* __restrict__ ws)
{
  constexpr size_t NQ = (size_t)Mtok * Dc;
  constexpr size_t NW = (size_t)Dc * Dc;
  const size_t e = ((size_t)blockIdx.x * 256 + threadIdx.x) * 8;
  const float* src; bf16* dst;
  if (e < 3 * NQ) {
    src = (e < NQ) ? q + e : (e < 2 * NQ) ? k + (e - NQ) : v + (e - 2 * NQ);
    dst = ws + e;
  } else {
    const size_t w = e - 3 * NQ;
    const float* wsrc = (w < NW) ? wq : (w < 2 * NW) ? wk : (w < 3 * NW) ? wv : wo;
    src = wsrc + (w & (NW - 1));
    dst = ws + 5 * NQ + w;
  }
  f32x4 a = ((const f32x4*)src)[0];
  f32x4 b = ((const f32x4*)src)[1];
  bf16x8 t;
  t[0]=(bf16)a[0]; t[1]=(bf16)a[1]; t[2]=(bf16)a[2]; t[3]=(bf16)a[3];
  t[4]=(bf16)b[0]; t[5]=(bf16)b[1]; t[6]=(bf16)b[2]; t[7]=(bf16)b[3];
  *(bf16x8*)dst = t;
}

// ---------------------------------------------------------------------------
// Fused Q/K/V projection GEMM: 128x128 tile, BK=32, XOR-swizzled LDS
// (conflict-free ds_read_b128), global_load_lds width=16. grid (32,8,3).
// Swizzle: global 16B chunk (c ^ ((row>>1)&3)) lands at physical slot (row,c);
// reader fetches physical chunk (quad ^ ((l16>>1)&3)). 16 lanes -> 8 bank
// groups -> 2 lanes/bank (free, m136).
// z==2 (V) writes output TRANSPOSED to Vt (B, D, S) with packed 8B stores.
// ---------------------------------------------------------------------------
__global__ __launch_bounds__(256) void gemm_qkv(
    const bf16* __restrict__ Aq, const bf16* __restrict__ Ak,
    const bf16* __restrict__ Av, const bf16* __restrict__ Wb,
    const float* __restrict__ bq, const float* __restrict__ bk,
    const float* __restrict__ bv,
    bf16* __restrict__ Yq, bf16* __restrict__ Yk, bf16* __restrict__ Vt)
{
  __shared__ __attribute__((aligned(16))) bf16 As[128 * 32];
  __shared__ __attribute__((aligned(16))) bf16 Bs[128 * 32];

  const int z = blockIdx.z;
  const bf16*  A    = (z == 0) ? Aq : (z == 1) ? Ak : Av;
  const bf16*  Wz   = Wb + (size_t)z * Dc * Dc;
  const float* bias = (z == 0) ? bq : (z == 1) ? bk : bv;

  const int m0 = blockIdx.x * 128, n0 = blockIdx.y * 128;
  const int tid = threadIdx.x, wave = tid >> 6, lane = tid & 63;
  const int quad = lane >> 4, l16 = lane & 15;
  const int rw = wave >> 1, cw = wave & 1;
  const int swz = (l16 >> 1) & 3;                    // reader swizzle
  const int srow   = tid >> 2;                       // staging row (0..63)
  const int gchunk = (((tid & 3) ^ ((tid >> 3) & 3))) * 8;  // swizzled src col

  f32x4 acc[4][4] = {};

  for (int k0 = 0; k0 < Dc; k0 += 32) {
#pragma unroll
    for (int p = 0; p < 2; ++p) {
      const int row = p * 64 + srow;
      gld_lds16(A  + (size_t)(m0 + row) * Dc + k0 + gchunk,
                &As[(p * 64 + wave * 16) * 32]);
      gld_lds16(Wz + (size_t)(n0 + row) * Dc + k0 + gchunk,
                &Bs[(p * 64 + wave * 16) * 32]);
    }
    __syncthreads();
    bf16x8 af[4];
#pragma unroll
    for (int rt = 0; rt < 4; ++rt)
      af[rt] = *(const bf16x8*)&As[(rw * 64 + rt * 16 + l16) * 32 + (quad ^ swz) * 8];
#pragma unroll
    for (int ct = 0; ct < 4; ++ct) {
      bf16x8 bfr = *(const bf16x8*)&Bs[(cw * 64 + ct * 16 + l16) * 32 + (quad ^ swz) * 8];
#pragma unroll
      for (int rt = 0; rt < 4; ++rt)
        acc[rt][ct] = __builtin_amdgcn_mfma_f32_16x16x32_bf16(af[rt], bfr, acc[rt][ct], 0, 0, 0);
    }
    __syncthreads();
  }

  if (z < 2) {
    bf16* Y = (z == 0) ? Yq : Yk;
#pragma unroll
    for (int ct = 0; ct < 4; ++ct) {
      const int col = n0 + cw * 64 + ct * 16 + l16;
      const float bvv = bias[col];
#pragma unroll
      for (int rt = 0; rt < 4; ++rt)
#pragma unroll
        for (int i = 0; i < 4; ++i) {
          const int row = m0 + rw * 64 + rt * 16 + quad * 4 + i;
          Y[(size_t)row * Dc + col] = (bf16)(acc[rt][ct][i] + bvv);
        }
    }
  } else {
    // V: write transposed -> Vt[(b*Dc + col)*Sc + s], i-axis contiguous
#pragma unroll
    for (int ct = 0; ct < 4; ++ct) {
      const int col = n0 + cw * 64 + ct * 16 + l16;
      const float bvv = bias[col];
#pragma unroll
      for (int rt = 0; rt < 4; ++rt) {
        const int row0 = m0 + rw * 64 + rt * 16 + quad * 4;  // multiple of 4
        const int bb = row0 >> 11, s0 = row0 & 2047;
        bf16x4 pk;
#pragma unroll
        for (int i = 0; i < 4; ++i) pk[i] = (bf16)(acc[rt][ct][i] + bvv);
        *(bf16x4*)&Vt[((size_t)bb * Dc + col) * Sc + s0] = pk;
      }
    }
  }
}

// ---------------------------------------------------------------------------
// O-projection GEMM: 64x128 tile, BK=32, XOR-swizzled LDS, fp32 out.
// 512 blocks (2/CU).
// ---------------------------------------------------------------------------
__global__ __launch_bounds__(256) void gemm_o(
    const bf16* __restrict__ A, const bf16* __restrict__ Wz,
    const float* __restrict__ bias, float* __restrict__ Y)
{
  __shared__ __attribute__((aligned(16))) bf16 As[64 * 32];
  __shared__ __attribute__((aligned(16))) bf16 Bs[128 * 32];

  const int m0 = blockIdx.x * 64, n0 = blockIdx.y * 128;
  const int tid = threadIdx.x, wave = tid >> 6, lane = tid & 63;
  const int quad = lane >> 4, l16 = lane & 15;
  const int swz = (l16 >> 1) & 3;
  const int srow   = tid >> 2;
  const int gchunk = (((tid & 3) ^ ((tid >> 3) & 3))) * 8;

  f32x4 acc[4][2] = {};

  for (int k0 = 0; k0 < Dc; k0 += 32) {
    gld_lds16(A + (size_t)(m0 + srow) * Dc + k0 + gchunk, &As[(wave * 16) * 32]);
#pragma unroll
    for (int p = 0; p < 2; ++p) {
      const int row = p * 64 + srow;
      gld_lds16(Wz + (size_t)(n0 + row) * Dc + k0 + gchunk,
                &Bs[(p * 64 + wave * 16) * 32]);
    }
    __syncthreads();
    bf16x8 af[4];
#pragma unroll
    for (int rt = 0; rt < 4; ++rt)
      af[rt] = *(const bf16x8*)&As[(rt * 16 + l16) * 32 + (quad ^ swz) * 8];
#pragma unroll
    for (int ct = 0; ct < 2; ++ct) {
      bf16x8 bfr = *(const bf16x8*)&Bs[(wave * 32 + ct * 16 + l16) * 32 + (quad ^ swz) * 8];
#pragma unroll
      for (int rt = 0; rt < 4; ++rt)
        acc[rt][ct] = __builtin_amdgcn_mfma_f32_16x16x32_bf16(af[rt], bfr, acc[rt][ct], 0, 0, 0);
    }
    __syncthreads();
  }

#pragma unroll
  for (int ct = 0; ct < 2; ++ct) {
    const int col = n0 + wave * 32 + ct * 16 + l16;
    const float bvv = bias[col];
#pragma unroll
    for (int rt = 0; rt < 4; ++rt)
#pragma unroll
      for (int i = 0; i < 4; ++i) {
        const int row = m0 + rt * 16 + quad * 4 + i;
        Y[(size_t)row * Dc + col] = acc[rt][ct][i] + bvv;
      }
  }
}

// ---------------------------------------------------------------------------
// Fallback GEMM (fp32-staging 128x128, reg prefetch) for small workspaces.
// ---------------------------------------------------------------------------
template <bool AF32, bool BF32, bool OUTF32>
__global__ __launch_bounds__(256) void gemm128(
    const void* __restrict__ Av, const void* __restrict__ Bv,
    const float* __restrict__ bias, void* __restrict__ Yv,
    int M, int N, int K)
{
  __shared__ __attribute__((aligned(16))) bf16 As[2][128][40];
  __shared__ __attribute__((aligned(16))) bf16 Bs[2][128][40];

  const int m0 = blockIdx.x * 128, n0 = blockIdx.y * 128;
  const int tid = threadIdx.x, wave = tid >> 6, lane = tid & 63;
  const int quad = lane >> 4, l16 = lane & 15;
  const int rw = wave >> 1, cw = wave & 1;
  const int srow = tid >> 1, sc = (tid & 1) * 16;

  f32x4 acc[4][4] = {};

  auto load = [&](const void* P, bool f32, int r0, int k0, bf16x8& lo, bf16x8& hi) {
    if (f32) {
      const float* s = (const float*)P + (size_t)(r0 + srow) * K + k0 + sc;
      f32x4 a0 = ((const f32x4*)s)[0], a1 = ((const f32x4*)s)[1];
      f32x4 a2 = ((const f32x4*)s)[2], a3 = ((const f32x4*)s)[3];
      lo[0]=(bf16)a0[0]; lo[1]=(bf16)a0[1]; lo[2]=(bf16)a0[2]; lo[3]=(bf16)a0[3];
      lo[4]=(bf16)a1[0]; lo[5]=(bf16)a1[1]; lo[6]=(bf16)a1[2]; lo[7]=(bf16)a1[3];
      hi[0]=(bf16)a2[0]; hi[1]=(bf16)a2[1]; hi[2]=(bf16)a2[2]; hi[3]=(bf16)a2[3];
      hi[4]=(bf16)a3[0]; hi[5]=(bf16)a3[1]; hi[6]=(bf16)a3[2]; hi[7]=(bf16)a3[3];
    } else {
      const bf16* s = (const bf16*)P + (size_t)(r0 + srow) * K + k0 + sc;
      lo = ((const bf16x8*)s)[0]; hi = ((const bf16x8*)s)[1];
    }
  };

  bf16x8 alo, ahi, blo, bhi;
  load(Av, AF32, m0, 0, alo, ahi); load(Bv, BF32, n0, 0, blo, bhi);
  *(bf16x8*)&As[0][srow][sc] = alo; *(bf16x8*)&As[0][srow][sc + 8] = ahi;
  *(bf16x8*)&Bs[0][srow][sc] = blo; *(bf16x8*)&Bs[0][srow][sc + 8] = bhi;

  const int NIT = K >> 5;
  for (int it = 0; it < NIT; ++it) {
    __syncthreads();
    const int cur = it & 1;
    const bool pf = (it + 1) < NIT;
    if (pf) { load(Av, AF32, m0, (it+1)*32, alo, ahi); load(Bv, BF32, n0, (it+1)*32, blo, bhi); }

    bf16x8 af[4];
#pragma unroll
    for (int rt = 0; rt < 4; ++rt)
      af[rt] = *(const bf16x8*)&As[cur][rw * 64 + rt * 16 + l16][quad * 8];
#pragma unroll
    for (int ct = 0; ct < 4; ++ct) {
      bf16x8 bfr = *(const bf16x8*)&Bs[cur][cw * 64 + ct * 16 + l16][quad * 8];
#pragma unroll
      for (int rt = 0; rt < 4; ++rt)
        acc[rt][ct] = __builtin_amdgcn_mfma_f32_16x16x32_bf16(af[rt], bfr, acc[rt][ct], 0, 0, 0);
    }
    if (pf) {
      const int nxt = cur ^ 1;
      *(bf16x8*)&As[nxt][srow][sc] = alo; *(bf16x8*)&As[nxt][srow][sc + 8] = ahi;
      *(bf16x8*)&Bs[nxt][srow][sc] = blo; *(bf16x8*)&Bs[nxt][srow][sc + 8] = bhi;
    }
  }

#pragma unroll
  for (int ct = 0; ct < 4; ++ct) {
    const int col = n0 + cw * 64 + ct * 16 + l16;
    const float bvv = bias[col];
#pragma unroll
    for (int rt = 0; rt < 4; ++rt)
#pragma unroll
      for (int i = 0; i < 4; ++i) {
        const int row = m0 + rw * 64 + rt * 16 + quad * 4 + i;
        const float vv = acc[rt][ct][i] + bvv;
        if constexpr (OUTF32) ((float*)Yv)[(size_t)row * N + col] = vv;
        else                  ((bf16*)Yv)[(size_t)row * N + col] = (bf16)vv;
      }
  }
}

// ---------------------------------------------------------------------------
// Transpose V (fallback path only): (B*S, D) -> (B, D, S).
// ---------------------------------------------------------------------------
__global__ __launch_bounds__(256) void transpose_v(
    const bf16* __restrict__ in, bf16* __restrict__ out)
{
  __shared__ __attribute__((aligned(16))) bf16 tile[64][72];
  const int s0 = blockIdx.x * 64, d0 = blockIdx.y * 64, b = blockIdx.z;
  const int t = threadIdx.x, r = t >> 2, c = (t & 3) * 16;

  const bf16* src = in + (size_t)(b * Sc + s0 + r) * Dc + d0 + c;
  *(bf16x8*)&tile[r][c]     = ((const bf16x8*)src)[0];
  *(bf16x8*)&tile[r][c + 8] = ((const bf16x8*)src)[1];
  __syncthreads();

  bf16x8 t0, t1;
#pragma unroll
  for (int j = 0; j < 8; ++j) t0[j] = tile[c + j][r];
#pragma unroll
  for (int j = 0; j < 8; ++j) t1[j] = tile[c + 8 + j][r];
  bf16* dst = out + (size_t)(b * Dc + d0 + r) * Sc + s0 + c;
  ((bf16x8*)dst)[0] = t0;
  ((bf16x8*)dst)[1] = t1;
}

// ---------------------------------------------------------------------------
// Causal flash attention v4 (unchanged from R4 — isolate the GEMM swizzle).
// ---------------------------------------------------------------------------
__global__ __launch_bounds__(256) void attn4(
    const bf16* __restrict__ Q, const bf16* __restrict__ K,
    const bf16* __restrict__ Vt, bf16* __restrict__ O)
{
  __shared__ __attribute__((aligned(16))) bf16 Ks[2][64][68];
  __shared__ __attribute__((aligned(16))) bf16 Vs[2][64][68];   // [d][key]
  __shared__ __attribute__((aligned(16))) bf16 Ps[4][16][68];   // per-wave

  const int bh = blockIdx.x, b = bh >> 4, h = bh & 15;
  const int qy = blockIdx.y;
  const int qt = (qy & 8) ? ((qy & 24) | (7 - (qy & 7))) : qy;
  const int q0 = qt * 64;
  const int nkb = qt + 1;

  const int tid = threadIdx.x, wave = tid >> 6, lane = tid & 63;
  const int quad = lane >> 4, l16 = lane & 15;
  const int sr = tid >> 2, sc4 = (tid & 3) * 16;

  const bf16 onec = (bf16)1.0f;
  const bf16x8 ones = {onec, onec, onec, onec, onec, onec, onec, onec};

  const bf16* qrow = Q + (size_t)(b * Sc + q0 + wave * 16 + l16) * Dc + h * 64 + quad * 8;
  const bf16x8 aq0 = *(const bf16x8*)qrow;
  const bf16x8 aq1 = *(const bf16x8*)(qrow + 32);

  f32x4 oacc[4] = {{0,0,0,0},{0,0,0,0},{0,0,0,0},{0,0,0,0}};
  f32x4 lacc = {0, 0, 0, 0};

  {
    const bf16* ksrc = K + (size_t)(b * Sc + sr) * Dc + h * 64 + sc4;
    ((bf16x8*)&Ks[0][sr][sc4])[0] = ((const bf16x8*)ksrc)[0];
    ((bf16x8*)&Ks[0][sr][sc4])[1] = ((const bf16x8*)ksrc)[1];
    const bf16* vsrc = Vt + (size_t)(b * Dc + h * 64 + sr) * Sc + sc4;
    ((bf16x8*)&Vs[0][sr][sc4])[0] = ((const bf16x8*)vsrc)[0];
    ((bf16x8*)&Vs[0][sr][sc4])[1] = ((const bf16x8*)vsrc)[1];
  }

  for (int kb = 0; kb < nkb; ++kb) {
    __syncthreads();
    const int cur = kb & 1;
    const bool pf = (kb + 1) < nkb;
    bf16x8 kp0, kp1, vp0, vp1;
    if (pf) {
      const bf16* ksrc = K + (size_t)(b * Sc + (kb + 1) * 64 + sr) * Dc + h * 64 + sc4;
      kp0 = ((const bf16x8*)ksrc)[0]; kp1 = ((const bf16x8*)ksrc)[1];
      const bf16* vsrc = Vt + (size_t)(b * Dc + h * 64 + sr) * Sc + (kb + 1) * 64 + sc4;
      vp0 = ((const bf16x8*)vsrc)[0]; vp1 = ((const bf16x8*)vsrc)[1];
    }

    // S^T = K * Q^T : A = K-frag (m=key), B = Q-frag (n=q)
    f32x4 s[4] = {{0,0,0,0},{0,0,0,0},{0,0,0,0},{0,0,0,0}};
#pragma unroll
    for (int d2 = 0; d2 < 2; ++d2) {
      const bf16x8 bq = d2 ? aq1 : aq0;
#pragma unroll
      for (int ct = 0; ct < 4; ++ct) {
        bf16x8 ak = *(const bf16x8*)&Ks[cur][ct * 16 + l16][d2 * 32 + quad * 8];
        s[ct] = __builtin_amdgcn_mfma_f32_16x16x32_bf16(ak, bq, s[ct], 0, 0, 0);
      }
    }

    if (kb == nkb - 1) {
      const int qcol = wave * 16 + l16;
#pragma unroll
      for (int ct = 0; ct < 4; ++ct) {
        const int key0 = ct * 16 + quad * 4;
        bf16x4 pk;
#pragma unroll
        for (int i = 0; i < 4; ++i)
          pk[i] = (bf16)((key0 + i > qcol) ? 0.f : __expf(s[ct][i] * 0.125f));
        *(bf16x4*)&Ps[wave][l16][key0] = pk;
      }
    } else {
#pragma unroll
      for (int ct = 0; ct < 4; ++ct) {
        bf16x4 pk;
#pragma unroll
        for (int i = 0; i < 4; ++i) pk[i] = (bf16)__expf(s[ct][i] * 0.125f);
        *(bf16x4*)&Ps[wave][l16][ct * 16 + quad * 4] = pk;
      }
    }

    const bf16x8 ap0 = *(const bf16x8*)&Ps[wave][l16][quad * 8];
    const bf16x8 ap1 = *(const bf16x8*)&Ps[wave][l16][32 + quad * 8];

    lacc = __builtin_amdgcn_mfma_f32_16x16x32_bf16(ap0, ones, lacc, 0, 0, 0);
    lacc = __builtin_amdgcn_mfma_f32_16x16x32_bf16(ap1, ones, lacc, 0, 0, 0);

#pragma unroll
    for (int d2 = 0; d2 < 2; ++d2) {
      const bf16x8 ap = d2 ? ap1 : ap0;
#pragma unroll
      for (int ct = 0; ct < 4; ++ct) {
        bf16x8 bv = *(const bf16x8*)&Vs[cur][ct * 16 + l16][d2 * 32 + quad * 8];
        oacc[ct] = __builtin_amdgcn_mfma_f32_16x16x32_bf16(ap, bv, oacc[ct], 0, 0, 0);
      }
    }

    if (pf) {
      const int nxt = cur ^ 1;
      ((bf16x8*)&Ks[nxt][sr][sc4])[0] = kp0; ((bf16x8*)&Ks[nxt][sr][sc4])[1] = kp1;
      ((bf16x8*)&Vs[nxt][sr][sc4])[0] = vp0; ((bf16x8*)&Vs[nxt][sr][sc4])[1] = vp1;
    }
  }

  f32x4 rl;
#pragma unroll
  for (int i = 0; i < 4; ++i) rl[i] = 1.0f / lacc[i];
#pragma unroll
  for (int ct = 0; ct < 4; ++ct)
#pragma unroll
    for (int i = 0; i < 4; ++i)
      O[(size_t)(b * Sc + q0 + wave * 16 + quad * 4 + i) * Dc + h * 64 + ct * 16 + l16] =
          (bf16)(oacc[ct][i] * rl[i]);
}

// ---------------------------------------------------------------------------
extern "C" void kernel_launch(void* const* d_in, const int* in_sizes, int n_in,
                              void* d_out, int out_size, void* d_ws, size_t ws_size,
                              hipStream_t stream)
{
  const float* q  = (const float*)d_in[0];
  const float* k  = (const float*)d_in[1];
  const float* v  = (const float*)d_in[2];
  // d_in[3] = causal tril mask — deterministic, applied analytically
  const float* wq = (const float*)d_in[4];
  const float* bq = (const float*)d_in[5];
  const float* wk = (const float*)d_in[6];
  const float* bk = (const float*)d_in[7];
  const float* wv = (const float*)d_in[8];
  const float* bv = (const float*)d_in[9];
  const float* wo = (const float*)d_in[10];
  const float* bo = (const float*)d_in[11];
  float* out = (float*)d_out;

  constexpr size_t NQ = (size_t)Mtok * Dc;
  constexpr size_t NW = (size_t)Dc * Dc;
  bf16* W = (bf16*)d_ws;
  const dim3 ga(Hc * Bc, 32);                // 1024 attn blocks
  const dim3 gt(Sc / 64, Dc / 64, Bc);

  const bool fancy = ws_size >= (size_t)(6 * NQ + 4 * NW) * 2;  // 58.7 MB
  if (fancy) {
    bf16* xq = W;             // dead after gemm_qkv -> reused as AO
    bf16* xk = W + NQ;
    bf16* xv = W + 2 * NQ;
    bf16* Qp = W + 3 * NQ;
    bf16* Kp = W + 4 * NQ;
    bf16* wb = W + 5 * NQ;    // wq,wk,wv,wo bf16 (4*NW)
    bf16* Vt = W + 5 * NQ + 4 * NW;  // fresh region (no aliasing with xv!)
    bf16* AO = W;             // reuse xq

    convert_all<<<8192, 256, 0, stream>>>(q, k, v, wq, wk, wv, wo, W);
    gemm_qkv<<<dim3(Mtok / 128, Dc / 128, 3), 256, 0, stream>>>(
        xq, xk, xv, wb, bq, bk, bv, Qp, Kp, Vt);
    attn4<<<ga, 256, 0, stream>>>(Qp, Kp, Vt, AO);
    gemm_o<<<dim3(Mtok / 64, Dc / 128), 256, 0, stream>>>(AO, wb + 3 * NW, bo, out);
  } else {
    // fallback: fp32 staging conversion inside the GEMMs, separate transpose
    bf16* Qp = W;
    bf16* Kp = W + NQ;
    bf16* Vp = W + 2 * NQ;
    bf16* Vt = W + 3 * NQ;
    bf16* AO = W + 4 * NQ;
    const dim3 gg(Mtok / 128, Dc / 128);
    gemm128<true, true, false><<<gg, 256, 0, stream>>>(q, wq, bq, Qp, Mtok, Dc, Dc);
    gemm128<true, true, false><<<gg, 256, 0, stream>>>(k, wk, bk, Kp, Mtok, Dc, Dc);
    gemm128<true, true, false><<<gg, 256, 0, stream>>>(v, wv, bv, Vp, Mtok, Dc, Dc);
    transpose_v<<<gt, 256, 0, stream>>>(Vp, Vt);
    attn4<<<ga, 256, 0, stream>>>(Qp, Kp, Vt, AO);
    gemm128<false, true, true><<<gg, 256, 0, stream>>>(AO, wo, bo, out, Mtok, Dc, Dc);
  }
}

// Round 6
// 228.063 us; speedup vs baseline: 1.0545x; 1.0308x over previous
//
#include <hip/hip_runtime.h>
#include <hip/hip_bf16.h>
#include <cstdint>

constexpr int Bc = 2, Sc = 2048, Dc = 1024, Hc = 16;
constexpr int Mtok = Bc * Sc;  // 4096 token rows

typedef __bf16 bf16;
typedef __bf16 bf16x4 __attribute__((ext_vector_type(4)));
typedef __bf16 bf16x8 __attribute__((ext_vector_type(8)));
typedef float  f32x4  __attribute__((ext_vector_type(4)));

// async global->LDS, 16B per lane; LDS dest = wave-uniform base + lane*16
__device__ __forceinline__ void gld_lds16(const bf16* g, bf16* l) {
  __builtin_amdgcn_global_load_lds(
      (__attribute__((address_space(1))) void*)(void*)g,
      (__attribute__((address_space(3))) void*)l, 16, 0, 0);
}

// ---------------------------------------------------------------------------
// One-time fp32 -> bf16 conversion of q,k,v and the 4 weight matrices.
// ---------------------------------------------------------------------------
__global__ __launch_bounds__(256) void convert_all(
    const float* __restrict__ q, const float* __restrict__ k,
    const float* __restrict__ v, const float* __restrict__ wq,
    const float* __restrict__ wk, const float* __restrict__ wv,
    const float* __restrict__ wo, bf16* __restrict__ ws)
{
  constexpr size_t NQ = (size_t)Mtok * Dc;
  constexpr size_t NW = (size_t)Dc * Dc;
  const size_t e = ((size_t)blockIdx.x * 256 + threadIdx.x) * 8;
  const float* src; bf16* dst;
  if (e < 3 * NQ) {
    src = (e < NQ) ? q + e : (e < 2 * NQ) ? k + (e - NQ) : v + (e - 2 * NQ);
    dst = ws + e;
  } else {
    const size_t w = e - 3 * NQ;
    const float* wsrc = (w < NW) ? wq : (w < 2 * NW) ? wk : (w < 3 * NW) ? wv : wo;
    src = wsrc + (w & (NW - 1));
    dst = ws + 5 * NQ + w;
  }
  f32x4 a = ((const f32x4*)src)[0];
  f32x4 b = ((const f32x4*)src)[1];
  bf16x8 t;
  t[0]=(bf16)a[0]; t[1]=(bf16)a[1]; t[2]=(bf16)a[2]; t[3]=(bf16)a[3];
  t[4]=(bf16)b[0]; t[5]=(bf16)b[1]; t[6]=(bf16)b[2]; t[7]=(bf16)b[3];
  *(bf16x8*)dst = t;
}

// ---------------------------------------------------------------------------
// Fused Q/K/V projection GEMM: 128x128 tile, BK=64 (16 barrier-drains vs 32),
// XOR-swizzled LDS (conflict-free ds_read_b128 at 128B row stride),
// global_load_lds width=16. grid (32,8,3). LDS 32KB single-buffered.
// Swizzle: staging instr covers 8 rows x 8 chunks; lane L holds global chunk
// g=(L&7)^(L>>3) of row base+(L>>3) -> physical slot (row, L&7) holds chunk
// (L&7)^(row&7). Reader fetches physical chunk (ks*4+quad)^(l16&7):
// 16 lanes -> 8 bank groups x2 = 2 lanes/bank (free, m136).
// z==2 (V) writes output TRANSPOSED to Vt (B, D, S) with packed 8B stores.
// ---------------------------------------------------------------------------
__global__ __launch_bounds__(256) void gemm_qkv(
    const bf16* __restrict__ Aq, const bf16* __restrict__ Ak,
    const bf16* __restrict__ Av, const bf16* __restrict__ Wb,
    const float* __restrict__ bq, const float* __restrict__ bk,
    const float* __restrict__ bv,
    bf16* __restrict__ Yq, bf16* __restrict__ Yk, bf16* __restrict__ Vt)
{
  __shared__ __attribute__((aligned(16))) bf16 As[128 * 64];
  __shared__ __attribute__((aligned(16))) bf16 Bs[128 * 64];

  const int z = blockIdx.z;
  const bf16*  A    = (z == 0) ? Aq : (z == 1) ? Ak : Av;
  const bf16*  Wz   = Wb + (size_t)z * Dc * Dc;
  const float* bias = (z == 0) ? bq : (z == 1) ? bk : bv;

  const int m0 = blockIdx.x * 128, n0 = blockIdx.y * 128;
  const int tid = threadIdx.x, wave = tid >> 6, lane = tid & 63;
  const int quad = lane >> 4, l16 = lane & 15;
  const int rw = wave >> 1, cw = wave & 1;
  const int swz = l16 & 7;                            // reader row swizzle
  const int srow = wave * 8 + (lane >> 3);            // staging row in 32-group
  const int scol = ((lane & 7) ^ (lane >> 3)) * 8;    // swizzled global chunk

  f32x4 acc[4][4] = {};

  for (int k0 = 0; k0 < Dc; k0 += 64) {
#pragma unroll
    for (int s = 0; s < 4; ++s) {
      gld_lds16(A  + (size_t)(m0 + s * 32 + srow) * Dc + k0 + scol,
                &As[(s * 32 + wave * 8) * 64]);
      gld_lds16(Wz + (size_t)(n0 + s * 32 + srow) * Dc + k0 + scol,
                &Bs[(s * 32 + wave * 8) * 64]);
    }
    __syncthreads();
#pragma unroll
    for (int ks = 0; ks < 2; ++ks) {
      bf16x8 af[4];
#pragma unroll
      for (int rt = 0; rt < 4; ++rt)
        af[rt] = *(const bf16x8*)
            &As[(rw * 64 + rt * 16 + l16) * 64 + (((ks * 4 + quad) ^ swz) * 8)];
#pragma unroll
      for (int ct = 0; ct < 4; ++ct) {
        bf16x8 bfr = *(const bf16x8*)
            &Bs[(cw * 64 + ct * 16 + l16) * 64 + (((ks * 4 + quad) ^ swz) * 8)];
#pragma unroll
        for (int rt = 0; rt < 4; ++rt)
          acc[rt][ct] = __builtin_amdgcn_mfma_f32_16x16x32_bf16(af[rt], bfr, acc[rt][ct], 0, 0, 0);
      }
    }
    __syncthreads();
  }

  if (z < 2) {
    bf16* Y = (z == 0) ? Yq : Yk;
#pragma unroll
    for (int ct = 0; ct < 4; ++ct) {
      const int col = n0 + cw * 64 + ct * 16 + l16;
      const float bvv = bias[col];
#pragma unroll
      for (int rt = 0; rt < 4; ++rt)
#pragma unroll
        for (int i = 0; i < 4; ++i) {
          const int row = m0 + rw * 64 + rt * 16 + quad * 4 + i;
          Y[(size_t)row * Dc + col] = (bf16)(acc[rt][ct][i] + bvv);
        }
    }
  } else {
    // V: write transposed -> Vt[(b*Dc + col)*Sc + s], i-axis contiguous
#pragma unroll
    for (int ct = 0; ct < 4; ++ct) {
      const int col = n0 + cw * 64 + ct * 16 + l16;
      const float bvv = bias[col];
#pragma unroll
      for (int rt = 0; rt < 4; ++rt) {
        const int row0 = m0 + rw * 64 + rt * 16 + quad * 4;  // multiple of 4
        const int bb = row0 >> 11, s0 = row0 & 2047;
        bf16x4 pk;
#pragma unroll
        for (int i = 0; i < 4; ++i) pk[i] = (bf16)(acc[rt][ct][i] + bvv);
        *(bf16x4*)&Vt[((size_t)bb * Dc + col) * Sc + s0] = pk;
      }
    }
  }
}

// ---------------------------------------------------------------------------
// O-projection GEMM: 64x128 tile, BK=64, XOR-swizzled LDS, fp32 out.
// 512 blocks (2/CU). LDS 24KB.
// ---------------------------------------------------------------------------
__global__ __launch_bounds__(256) void gemm_o(
    const bf16* __restrict__ A, const bf16* __restrict__ Wz,
    const float* __restrict__ bias, float* __restrict__ Y)
{
  __shared__ __attribute__((aligned(16))) bf16 As[64 * 64];
  __shared__ __attribute__((aligned(16))) bf16 Bs[128 * 64];

  const int m0 = blockIdx.x * 64, n0 = blockIdx.y * 128;
  const int tid = threadIdx.x, wave = tid >> 6, lane = tid & 63;
  const int quad = lane >> 4, l16 = lane & 15;
  const int swz = l16 & 7;
  const int srow = wave * 8 + (lane >> 3);
  const int scol = ((lane & 7) ^ (lane >> 3)) * 8;

  f32x4 acc[4][2] = {};

  for (int k0 = 0; k0 < Dc; k0 += 64) {
#pragma unroll
    for (int s = 0; s < 2; ++s)
      gld_lds16(A + (size_t)(m0 + s * 32 + srow) * Dc + k0 + scol,
                &As[(s * 32 + wave * 8) * 64]);
#pragma unroll
    for (int s = 0; s < 4; ++s)
      gld_lds16(Wz + (size_t)(n0 + s * 32 + srow) * Dc + k0 + scol,
                &Bs[(s * 32 + wave * 8) * 64]);
    __syncthreads();
#pragma unroll
    for (int ks = 0; ks < 2; ++ks) {
      bf16x8 af[4];
#pragma unroll
      for (int rt = 0; rt < 4; ++rt)
        af[rt] = *(const bf16x8*)
            &As[(rt * 16 + l16) * 64 + (((ks * 4 + quad) ^ swz) * 8)];
#pragma unroll
      for (int ct = 0; ct < 2; ++ct) {
        bf16x8 bfr = *(const bf16x8*)
            &Bs[(wave * 32 + ct * 16 + l16) * 64 + (((ks * 4 + quad) ^ swz) * 8)];
#pragma unroll
        for (int rt = 0; rt < 4; ++rt)
          acc[rt][ct] = __builtin_amdgcn_mfma_f32_16x16x32_bf16(af[rt], bfr, acc[rt][ct], 0, 0, 0);
      }
    }
    __syncthreads();
  }

#pragma unroll
  for (int ct = 0; ct < 2; ++ct) {
    const int col = n0 + wave * 32 + ct * 16 + l16;
    const float bvv = bias[col];
#pragma unroll
    for (int rt = 0; rt < 4; ++rt)
#pragma unroll
      for (int i = 0; i < 4; ++i) {
        const int row = m0 + rt * 16 + quad * 4 + i;
        Y[(size_t)row * Dc + col] = acc[rt][ct][i] + bvv;
      }
  }
}

// ---------------------------------------------------------------------------
// Fallback GEMM (fp32-staging 128x128, reg prefetch) for small workspaces.
// ---------------------------------------------------------------------------
template <bool AF32, bool BF32, bool OUTF32>
__global__ __launch_bounds__(256) void gemm128(
    const void* __restrict__ Av, const void* __restrict__ Bv,
    const float* __restrict__ bias, void* __restrict__ Yv,
    int M, int N, int K)
{
  __shared__ __attribute__((aligned(16))) bf16 As[2][128][40];
  __shared__ __attribute__((aligned(16))) bf16 Bs[2][128][40];

  const int m0 = blockIdx.x * 128, n0 = blockIdx.y * 128;
  const int tid = threadIdx.x, wave = tid >> 6, lane = tid & 63;
  const int quad = lane >> 4, l16 = lane & 15;
  const int rw = wave >> 1, cw = wave & 1;
  const int srow = tid >> 1, sc = (tid & 1) * 16;

  f32x4 acc[4][4] = {};

  auto load = [&](const void* P, bool f32, int r0, int k0, bf16x8& lo, bf16x8& hi) {
    if (f32) {
      const float* s = (const float*)P + (size_t)(r0 + srow) * K + k0 + sc;
      f32x4 a0 = ((const f32x4*)s)[0], a1 = ((const f32x4*)s)[1];
      f32x4 a2 = ((const f32x4*)s)[2], a3 = ((const f32x4*)s)[3];
      lo[0]=(bf16)a0[0]; lo[1]=(bf16)a0[1]; lo[2]=(bf16)a0[2]; lo[3]=(bf16)a0[3];
      lo[4]=(bf16)a1[0]; lo[5]=(bf16)a1[1]; lo[6]=(bf16)a1[2]; lo[7]=(bf16)a1[3];
      hi[0]=(bf16)a2[0]; hi[1]=(bf16)a2[1]; hi[2]=(bf16)a2[2]; hi[3]=(bf16)a2[3];
      hi[4]=(bf16)a3[0]; hi[5]=(bf16)a3[1]; hi[6]=(bf16)a3[2]; hi[7]=(bf16)a3[3];
    } else {
      const bf16* s = (const bf16*)P + (size_t)(r0 + srow) * K + k0 + sc;
      lo = ((const bf16x8*)s)[0]; hi = ((const bf16x8*)s)[1];
    }
  };

  bf16x8 alo, ahi, blo, bhi;
  load(Av, AF32, m0, 0, alo, ahi); load(Bv, BF32, n0, 0, blo, bhi);
  *(bf16x8*)&As[0][srow][sc] = alo; *(bf16x8*)&As[0][srow][sc + 8] = ahi;
  *(bf16x8*)&Bs[0][srow][sc] = blo; *(bf16x8*)&Bs[0][srow][sc + 8] = bhi;

  const int NIT = K >> 5;
  for (int it = 0; it < NIT; ++it) {
    __syncthreads();
    const int cur = it & 1;
    const bool pf = (it + 1) < NIT;
    if (pf) { load(Av, AF32, m0, (it+1)*32, alo, ahi); load(Bv, BF32, n0, (it+1)*32, blo, bhi); }

    bf16x8 af[4];
#pragma unroll
    for (int rt = 0; rt < 4; ++rt)
      af[rt] = *(const bf16x8*)&As[cur][rw * 64 + rt * 16 + l16][quad * 8];
#pragma unroll
    for (int ct = 0; ct < 4; ++ct) {
      bf16x8 bfr = *(const bf16x8*)&Bs[cur][cw * 64 + ct * 16 + l16][quad * 8];
#pragma unroll
      for (int rt = 0; rt < 4; ++rt)
        acc[rt][ct] = __builtin_amdgcn_mfma_f32_16x16x32_bf16(af[rt], bfr, acc[rt][ct], 0, 0, 0);
    }
    if (pf) {
      const int nxt = cur ^ 1;
      *(bf16x8*)&As[nxt][srow][sc] = alo; *(bf16x8*)&As[nxt][srow][sc + 8] = ahi;
      *(bf16x8*)&Bs[nxt][srow][sc] = blo; *(bf16x8*)&Bs[nxt][srow][sc + 8] = bhi;
    }
  }

#pragma unroll
  for (int ct = 0; ct < 4; ++ct) {
    const int col = n0 + cw * 64 + ct * 16 + l16;
    const float bvv = bias[col];
#pragma unroll
    for (int rt = 0; rt < 4; ++rt)
#pragma unroll
      for (int i = 0; i < 4; ++i) {
        const int row = m0 + rw * 64 + rt * 16 + quad * 4 + i;
        const float vv = acc[rt][ct][i] + bvv;
        if constexpr (OUTF32) ((float*)Yv)[(size_t)row * N + col] = vv;
        else                  ((bf16*)Yv)[(size_t)row * N + col] = (bf16)vv;
      }
  }
}

// ---------------------------------------------------------------------------
// Transpose V (fallback path only): (B*S, D) -> (B, D, S).
// ---------------------------------------------------------------------------
__global__ __launch_bounds__(256) void transpose_v(
    const bf16* __restrict__ in, bf16* __restrict__ out)
{
  __shared__ __attribute__((aligned(16))) bf16 tile[64][72];
  const int s0 = blockIdx.x * 64, d0 = blockIdx.y * 64, b = blockIdx.z;
  const int t = threadIdx.x, r = t >> 2, c = (t & 3) * 16;

  const bf16* src = in + (size_t)(b * Sc + s0 + r) * Dc + d0 + c;
  *(bf16x8*)&tile[r][c]     = ((const bf16x8*)src)[0];
  *(bf16x8*)&tile[r][c + 8] = ((const bf16x8*)src)[1];
  __syncthreads();

  bf16x8 t0, t1;
#pragma unroll
  for (int j = 0; j < 8; ++j) t0[j] = tile[c + j][r];
#pragma unroll
  for (int j = 0; j < 8; ++j) t1[j] = tile[c + 8 + j][r];
  bf16* dst = out + (size_t)(b * Dc + d0 + r) * Sc + s0 + c;
  ((bf16x8*)dst)[0] = t0;
  ((bf16x8*)dst)[1] = t1;
}

// ---------------------------------------------------------------------------
// Causal flash attention v4 (unchanged — isolate the GEMM BK=64 change).
// ---------------------------------------------------------------------------
__global__ __launch_bounds__(256) void attn4(
    const bf16* __restrict__ Q, const bf16* __restrict__ K,
    const bf16* __restrict__ Vt, bf16* __restrict__ O)
{
  __shared__ __attribute__((aligned(16))) bf16 Ks[2][64][68];
  __shared__ __attribute__((aligned(16))) bf16 Vs[2][64][68];   // [d][key]
  __shared__ __attribute__((aligned(16))) bf16 Ps[4][16][68];   // per-wave

  const int bh = blockIdx.x, b = bh >> 4, h = bh & 15;
  const int qy = blockIdx.y;
  const int qt = (qy & 8) ? ((qy & 24) | (7 - (qy & 7))) : qy;
  const int q0 = qt * 64;
  const int nkb = qt + 1;

  const int tid = threadIdx.x, wave = tid >> 6, lane = tid & 63;
  const int quad = lane >> 4, l16 = lane & 15;
  const int sr = tid >> 2, sc4 = (tid & 3) * 16;

  const bf16 onec = (bf16)1.0f;
  const bf16x8 ones = {onec, onec, onec, onec, onec, onec, onec, onec};

  const bf16* qrow = Q + (size_t)(b * Sc + q0 + wave * 16 + l16) * Dc + h * 64 + quad * 8;
  const bf16x8 aq0 = *(const bf16x8*)qrow;
  const bf16x8 aq1 = *(const bf16x8*)(qrow + 32);

  f32x4 oacc[4] = {{0,0,0,0},{0,0,0,0},{0,0,0,0},{0,0,0,0}};
  f32x4 lacc = {0, 0, 0, 0};

  {
    const bf16* ksrc = K + (size_t)(b * Sc + sr) * Dc + h * 64 + sc4;
    ((bf16x8*)&Ks[0][sr][sc4])[0] = ((const bf16x8*)ksrc)[0];
    ((bf16x8*)&Ks[0][sr][sc4])[1] = ((const bf16x8*)ksrc)[1];
    const bf16* vsrc = Vt + (size_t)(b * Dc + h * 64 + sr) * Sc + sc4;
    ((bf16x8*)&Vs[0][sr][sc4])[0] = ((const bf16x8*)vsrc)[0];
    ((bf16x8*)&Vs[0][sr][sc4])[1] = ((const bf16x8*)vsrc)[1];
  }

  for (int kb = 0; kb < nkb; ++kb) {
    __syncthreads();
    const int cur = kb & 1;
    const bool pf = (kb + 1) < nkb;
    bf16x8 kp0, kp1, vp0, vp1;
    if (pf) {
      const bf16* ksrc = K + (size_t)(b * Sc + (kb + 1) * 64 + sr) * Dc + h * 64 + sc4;
      kp0 = ((const bf16x8*)ksrc)[0]; kp1 = ((const bf16x8*)ksrc)[1];
      const bf16* vsrc = Vt + (size_t)(b * Dc + h * 64 + sr) * Sc + (kb + 1) * 64 + sc4;
      vp0 = ((const bf16x8*)vsrc)[0]; vp1 = ((const bf16x8*)vsrc)[1];
    }

    // S^T = K * Q^T : A = K-frag (m=key), B = Q-frag (n=q)
    f32x4 s[4] = {{0,0,0,0},{0,0,0,0},{0,0,0,0},{0,0,0,0}};
#pragma unroll
    for (int d2 = 0; d2 < 2; ++d2) {
      const bf16x8 bq = d2 ? aq1 : aq0;
#pragma unroll
      for (int ct = 0; ct < 4; ++ct) {
        bf16x8 ak = *(const bf16x8*)&Ks[cur][ct * 16 + l16][d2 * 32 + quad * 8];
        s[ct] = __builtin_amdgcn_mfma_f32_16x16x32_bf16(ak, bq, s[ct], 0, 0, 0);
      }
    }

    if (kb == nkb - 1) {
      const int qcol = wave * 16 + l16;
#pragma unroll
      for (int ct = 0; ct < 4; ++ct) {
        const int key0 = ct * 16 + quad * 4;
        bf16x4 pk;
#pragma unroll
        for (int i = 0; i < 4; ++i)
          pk[i] = (bf16)((key0 + i > qcol) ? 0.f : __expf(s[ct][i] * 0.125f));
        *(bf16x4*)&Ps[wave][l16][key0] = pk;
      }
    } else {
#pragma unroll
      for (int ct = 0; ct < 4; ++ct) {
        bf16x4 pk;
#pragma unroll
        for (int i = 0; i < 4; ++i) pk[i] = (bf16)__expf(s[ct][i] * 0.125f);
        *(bf16x4*)&Ps[wave][l16][ct * 16 + quad * 4] = pk;
      }
    }

    const bf16x8 ap0 = *(const bf16x8*)&Ps[wave][l16][quad * 8];
    const bf16x8 ap1 = *(const bf16x8*)&Ps[wave][l16][32 + quad * 8];

    lacc = __builtin_amdgcn_mfma_f32_16x16x32_bf16(ap0, ones, lacc, 0, 0, 0);
    lacc = __builtin_amdgcn_mfma_f32_16x16x32_bf16(ap1, ones, lacc, 0, 0, 0);

#pragma unroll
    for (int d2 = 0; d2 < 2; ++d2) {
      const bf16x8 ap = d2 ? ap1 : ap0;
#pragma unroll
      for (int ct = 0; ct < 4; ++ct) {
        bf16x8 bv = *(const bf16x8*)&Vs[cur][ct * 16 + l16][d2 * 32 + quad * 8];
        oacc[ct] = __builtin_amdgcn_mfma_f32_16x16x32_bf16(ap, bv, oacc[ct], 0, 0, 0);
      }
    }

    if (pf) {
      const int nxt = cur ^ 1;
      ((bf16x8*)&Ks[nxt][sr][sc4])[0] = kp0; ((bf16x8*)&Ks[nxt][sr][sc4])[1] = kp1;
      ((bf16x8*)&Vs[nxt][sr][sc4])[0] = vp0; ((bf16x8*)&Vs[nxt][sr][sc4])[1] = vp1;
    }
  }

  f32x4 rl;
#pragma unroll
  for (int i = 0; i < 4; ++i) rl[i] = 1.0f / lacc[i];
#pragma unroll
  for (int ct = 0; ct < 4; ++ct)
#pragma unroll
    for (int i = 0; i < 4; ++i)
      O[(size_t)(b * Sc + q0 + wave * 16 + quad * 4 + i) * Dc + h * 64 + ct * 16 + l16] =
          (bf16)(oacc[ct][i] * rl[i]);
}

// ---------------------------------------------------------------------------
extern "C" void kernel_launch(void* const* d_in, const int* in_sizes, int n_in,
                              void* d_out, int out_size, void* d_ws, size_t ws_size,
                              hipStream_t stream)
{
  const float* q  = (const float*)d_in[0];
  const float* k  = (const float*)d_in[1];
  const float* v  = (const float*)d_in[2];
  // d_in[3] = causal tril mask — deterministic, applied analytically
  const float* wq = (const float*)d_in[4];
  const float* bq = (const float*)d_in[5];
  const float* wk = (const float*)d_in[6];
  const float* bk = (const float*)d_in[7];
  const float* wv = (const float*)d_in[8];
  const float* bv = (const float*)d_in[9];
  const float* wo = (const float*)d_in[10];
  const float* bo = (const float*)d_in[11];
  float* out = (float*)d_out;

  constexpr size_t NQ = (size_t)Mtok * Dc;
  constexpr size_t NW = (size_t)Dc * Dc;
  bf16* W = (bf16*)d_ws;
  const dim3 ga(Hc * Bc, 32);                // 1024 attn blocks
  const dim3 gt(Sc / 64, Dc / 64, Bc);

  const bool fancy = ws_size >= (size_t)(6 * NQ + 4 * NW) * 2;  // 58.7 MB
  if (fancy) {
    bf16* xq = W;             // dead after gemm_qkv -> reused as AO
    bf16* xk = W + NQ;
    bf16* xv = W + 2 * NQ;
    bf16* Qp = W + 3 * NQ;
    bf16* Kp = W + 4 * NQ;
    bf16* wb = W + 5 * NQ;    // wq,wk,wv,wo bf16 (4*NW)
    bf16* Vt = W + 5 * NQ + 4 * NW;  // fresh region (no aliasing with xv!)
    bf16* AO = W;             // reuse xq

    convert_all<<<8192, 256, 0, stream>>>(q, k, v, wq, wk, wv, wo, W);
    gemm_qkv<<<dim3(Mtok / 128, Dc / 128, 3), 256, 0, stream>>>(
        xq, xk, xv, wb, bq, bk, bv, Qp, Kp, Vt);
    attn4<<<ga, 256, 0, stream>>>(Qp, Kp, Vt, AO);
    gemm_o<<<dim3(Mtok / 64, Dc / 128), 256, 0, stream>>>(AO, wb + 3 * NW, bo, out);
  } else {
    // fallback: fp32 staging conversion inside the GEMMs, separate transpose
    bf16* Qp = W;
    bf16* Kp = W + NQ;
    bf16* Vp = W + 2 * NQ;
    bf16* Vt = W + 3 * NQ;
    bf16* AO = W + 4 * NQ;
    const dim3 gg(Mtok / 128, Dc / 128);
    gemm128<true, true, false><<<gg, 256, 0, stream>>>(q, wq, bq, Qp, Mtok, Dc, Dc);
    gemm128<true, true, false><<<gg, 256, 0, stream>>>(k, wk, bk, Kp, Mtok, Dc, Dc);
    gemm128<true, true, false><<<gg, 256, 0, stream>>>(v, wv, bv, Vp, Mtok, Dc, Dc);
    transpose_v<<<gt, 256, 0, stream>>>(Vp, Vt);
    attn4<<<ga, 256, 0, stream>>>(Qp, Kp, Vt, AO);
    gemm128<false, true, true><<<gg, 256, 0, stream>>>(AO, wo, bo, out, Mtok, Dc, Dc);
  }
}